// Round 2
// baseline (1555.252 us; speedup 1.0000x reference)
//
#include <hip/hip_runtime.h>

// Entropic Sinkhorn EMD, B=2, N=4096, D=3, EPS=0.1, 20 iters.
// Round-8: round-7's fusion theory (42 dispatches -> persistent kernel) but
// with a PLAIN launch + manual two-level grid barrier instead of
// hipLaunchCooperativeKernel (round-7 failed with absmax ~= full ref value,
// i.e. the coop launch never ran under the harness). Barrier: 32 padded
// sub-counters (parallel atomic arrival) + 1 top counter, monotonic targets,
// zeroed by prep each launch (graph-replay safe). Agent-scope ACQ_REL RMWs
// write back the arriving XCD's L2; an acquire fence after the spin
// invalidates the waiter's caches -> cross-XCD visibility of pack.w/f/g.
// Phase math is bit-identical to the verified round-6 kernels.

#define N     4096
#define NT    256
#define RPB   8      // rows per block -> grid (512, 2) = 1024 blocks = 4/CU
#define NSUB  32     // sub-counter groups (1024/32 = 32 blocks each)
#define GRPSZ 32
#define SUBSTRIDE 16 // 64B padding between sub-counters

constexpr float EPS_F  = 0.1f;
constexpr float SHIFT  = 60.0f;
constexpr float LOG_A  = -8.317766166719343f;   // -log(4096)
constexpr float C10L   = 14.426950408889634f;   // 10*log2(e)
constexpr float C20L   = 28.853900817779268f;   // 20*log2(e)
constexpr float SHIFTL = 86.56170245333781f;    // SHIFT*log2(e)
constexpr float NLN2T  = -0.06931471805599453f; // -ln2/10
constexpr float LN2    = 0.6931471805599453f;

extern "C" __device__ float __ocml_native_exp2_f32(float);

__device__ __forceinline__ float fast_exp2(float x) {
#if __has_builtin(__builtin_amdgcn_exp2f)
    return __builtin_amdgcn_exp2f(x);
#else
    return __ocml_native_exp2_f32(x);
#endif
}

__device__ __forceinline__ float rfl(float x) {
    return __int_as_float(__builtin_amdgcn_readfirstlane(__float_as_int(x)));
}

// Pack {x,y,z, h2(g=0) = SHIFTL - 10L|p|^2}; wBase = -10L|p|^2; zero f,g,out
// and the grid-barrier counters (so every launch / graph replay starts clean).
__global__ __launch_bounds__(256) void prep_kernel(
    const float* __restrict__ gen, const float* __restrict__ gt,
    float4* __restrict__ genPack, float4* __restrict__ gtPack,
    float* __restrict__ wBaseGen, float* __restrict__ wBaseGt,
    float* __restrict__ fg, float* __restrict__ out,
    unsigned* __restrict__ bar)
{
    int t = blockIdx.x * 256 + threadIdx.x;   // 0 .. 16383
    if (t < NSUB * SUBSTRIDE + SUBSTRIDE) bar[t] = 0u;
    int cloud = t >> 13;
    int idx   = t & 8191;                     // b*N + j
    const float* src = cloud ? gt : gen;
    float x = src[idx * 3 + 0];
    float y = src[idx * 3 + 1];
    float z = src[idx * 3 + 2];
    float nb = -C10L * fmaf(z, z, fmaf(y, y, x * x));   // -10L|p|^2
    (cloud ? gtPack : genPack)[idx] = make_float4(x, y, z, SHIFTL + nb);
    (cloud ? wBaseGt : wBaseGen)[idx] = nb;
    fg[t] = 0.0f;                             // f[2][N] then g[2][N]
    if (t == 0) out[0] = 0.0f;
}

// Two-level monotonic grid barrier. phase = 0..39. All 1024 blocks call it
// the same number of times; counters monotonically increase within a launch.
__device__ __forceinline__ void grid_bar(unsigned* __restrict__ bar,
                                         int phase, int subidx)
{
    __syncthreads();   // drain this block's stores (compiler emits vmcnt(0))
    if (threadIdx.x == 0) {
        unsigned* sub = bar + subidx * SUBSTRIDE;
        unsigned* top = bar + NSUB * SUBSTRIDE;
        // release: write back this XCD's L2 so our dual/pack.w stores are
        // visible at the coherence point before the arrival is observable.
        unsigned prev = __hip_atomic_fetch_add(
            sub, 1u, __ATOMIC_ACQ_REL, __HIP_MEMORY_SCOPE_AGENT);
        if (prev == (unsigned)(phase + 1) * GRPSZ - 1u) {
            __hip_atomic_fetch_add(
                top, 1u, __ATOMIC_ACQ_REL, __HIP_MEMORY_SCOPE_AGENT);
        }
        unsigned ttar = (unsigned)(phase + 1) * NSUB;
        while (__hip_atomic_load(top, __ATOMIC_RELAXED,
                                 __HIP_MEMORY_SCOPE_AGENT) < ttar) {
            __builtin_amdgcn_s_sleep(8);
        }
        // acquire: invalidate this CU/XCD's caches so next-phase reads of
        // pack.w / f / g fetch fresh data from the coherence point.
        __builtin_amdgcn_fence(__ATOMIC_ACQUIRE, "agent");
    }
    __syncthreads();
}

// One half-sweep, math/order identical to the verified round-6 sweep_kernel.
// Row constants are hoisted (loop-invariant) and passed in.
__device__ __forceinline__ void half_sweep(
    float4*       __restrict__ packRow,
    const float4* __restrict__ packCol,
    const float*  __restrict__ wBaseRow,
    float*        __restrict__ dualRaw,
    const float (&X)[RPB], const float (&Y)[RPB],
    const float (&Z)[RPB], const float (&S)[RPB],
    int b, int tid, int rowBase, float (&sred)[RPB][4])
{
    float4*      rp = packRow  + (size_t)b * N + rowBase;
    const float* wb = wBaseRow + (size_t)b * N + rowBase;
    const float4* cp = packCol + (size_t)b * N;

    float acc[RPB];
    #pragma unroll
    for (int r = 0; r < RPB; ++r) acc[r] = 0.0f;

    #pragma unroll 2
    for (int k = 0; k < N / NT; ++k) {
        float4 p = cp[tid + NT * k];       // {xj, yj, zj, h2j}
        #pragma unroll
        for (int r = 0; r < RPB; ++r) {
            float t = fmaf(Z[r], p.z, p.w);
            t = fmaf(Y[r], p.y, t);
            t = fmaf(X[r], p.x, t);
            acc[r] += fast_exp2(t + S[r]);
        }
    }

    #pragma unroll
    for (int r = 0; r < RPB; ++r) {
        float a = acc[r];
        a += __shfl_xor(a, 32);
        a += __shfl_xor(a, 16);
        a += __shfl_xor(a, 8);
        a += __shfl_xor(a, 4);
        a += __shfl_xor(a, 2);
        a += __shfl_xor(a, 1);
        acc[r] = a;
    }
    const int wave = tid >> 6, lane = tid & 63;
    if (lane == 0) {
        #pragma unroll
        for (int r = 0; r < RPB; ++r) sred[r][wave] = acc[r];
    }
    __syncthreads();
    if (tid < RPB) {
        float s = (sred[tid][0] + sred[tid][1]) + (sred[tid][2] + sred[tid][3]);
        float dual = EPS_F * (LOG_A + SHIFT - log2f(s) * LN2);
        dualRaw[(size_t)b * N + rowBase + tid] = dual;
        // refresh h2 for when this cloud serves as the column next phase
        ((float*)(rp + tid))[3] = fmaf(dual, C10L, SHIFTL + wb[tid]);
    }
    // sred reuse across phases is protected by the following grid_bar
}

__global__ __launch_bounds__(NT, 4) void sinkhorn_main(
    float4* __restrict__ genPack, float4* __restrict__ gtPack,
    const float* __restrict__ wBaseGen, const float* __restrict__ wBaseGt,
    float* __restrict__ f, float* __restrict__ g,
    unsigned* __restrict__ bar, float* __restrict__ out)
{
    const int b       = blockIdx.y;
    const int tid     = threadIdx.x;
    const int rowBase = blockIdx.x * RPB;
    const int bid     = b * (N / RPB) + blockIdx.x;   // 0..1023
    const int subidx  = bid >> 5;                      // 0..31
    __shared__ float sred[RPB][4];

    // Hoisted row constants for both phases (invariant across iterations;
    // written by prep_kernel, coherent via the kernel boundary).
    const float4* rpG = genPack  + (size_t)b * N + rowBase;
    const float4* rpT = gtPack   + (size_t)b * N + rowBase;
    const float*  wbG = wBaseGen + (size_t)b * N + rowBase;
    const float*  wbT = wBaseGt  + (size_t)b * N + rowBase;

    float XG[RPB], YG[RPB], ZG[RPB], SG[RPB];
    float XT[RPB], YT[RPB], ZT[RPB], ST[RPB];
    #pragma unroll
    for (int r = 0; r < RPB; ++r) {
        float4 q = rpG[r];
        XG[r] = rfl(q.x * C20L);
        YG[r] = rfl(q.y * C20L);
        ZG[r] = rfl(q.z * C20L);
        SG[r] = rfl(wbG[r]);
    }
    #pragma unroll
    for (int r = 0; r < RPB; ++r) {
        float4 q = rpT[r];
        XT[r] = rfl(q.x * C20L);
        YT[r] = rfl(q.y * C20L);
        ZT[r] = rfl(q.z * C20L);
        ST[r] = rfl(wbT[r]);
    }

    int phase = 0;
    #pragma unroll 1
    for (int it = 0; it < 20; ++it) {
        // f update: rows = gen, cols = gt (reads gtPack.w = h2(g))
        half_sweep(genPack, gtPack, wBaseGen, f,
                   XG, YG, ZG, SG, b, tid, rowBase, sred);
        grid_bar(bar, phase++, subidx);
        // g update: rows = gt, cols = gen (reads genPack.w = h2(f))
        half_sweep(gtPack, genPack, wBaseGt, g,
                   XT, YT, ZT, ST, b, tid, rowBase, sred);
        grid_bar(bar, phase++, subidx);
    }

    // ---- loss: += 0.5 * sum_ij exp((f_i + g_j - C_ij)/EPS) * C_ij
    {
        const float* fp = f + (size_t)b * N + rowBase;

        float Ax[RPB], Ay[RPB], Az[RPB], Ri[RPB], F2[RPB];
        #pragma unroll
        for (int r = 0; r < RPB; ++r) {
            float4 q = rpG[r];
            Ax[r] = rfl(q.x * -2.0f);
            Ay[r] = rfl(q.y * -2.0f);
            Az[r] = rfl(q.z * -2.0f);
            Ri[r] = rfl(wbG[r] * NLN2T);       // |p_i|^2
            F2[r] = rfl(fp[r] * C10L);
        }

        const float4* cp = gtPack + (size_t)b * N;
        const float*  gc = g      + (size_t)b * N;

        float acc = 0.0f;
        #pragma unroll 2
        for (int k = 0; k < N / NT; ++k) {
            float4 p  = cp[tid + NT * k];
            float  gj = gc[tid + NT * k];
            float  G2 = gj * C10L;
            float  rj = fmaf(p.w - SHIFTL, NLN2T, gj);   // |p_j|^2
            #pragma unroll
            for (int r = 0; r < RPB; ++r) {
                float cc = rj + Ri[r];
                cc = fmaf(Az[r], p.z, cc);
                cc = fmaf(Ay[r], p.y, cc);
                cc = fmaf(Ax[r], p.x, cc);
                float arg = fmaf(cc, -C10L, G2 + F2[r]);
                acc = fmaf(fast_exp2(arg), cc, acc);
            }
        }

        acc += __shfl_xor(acc, 32);
        acc += __shfl_xor(acc, 16);
        acc += __shfl_xor(acc, 8);
        acc += __shfl_xor(acc, 4);
        acc += __shfl_xor(acc, 2);
        acc += __shfl_xor(acc, 1);
        const int wave = tid >> 6, lane = tid & 63;
        if (lane == 0) sred[0][wave] = acc;
        __syncthreads();
        if (tid == 0) {
            float t2 = (sred[0][0] + sred[0][1]) + (sred[0][2] + sred[0][3]);
            atomicAdd(out, t2 * 0.5f);
        }
    }
}

extern "C" void kernel_launch(void* const* d_in, const int* in_sizes, int n_in,
                              void* d_out, int out_size, void* d_ws, size_t ws_size,
                              hipStream_t stream) {
    const float* gen = (const float*)d_in[0];
    const float* gt  = (const float*)d_in[1];
    float* out = (float*)d_out;

    char* ws = (char*)d_ws;
    float4*   genPack  = (float4*)ws;                        // 128 KB
    float4*   gtPack   = (float4*)(ws + 128 * 1024);         // 128 KB
    float*    wBaseGen = (float*)(ws + 256 * 1024);          // 32 KB
    float*    wBaseGt  = (float*)(ws + 288 * 1024);          // 32 KB
    float*    f        = (float*)(ws + 320 * 1024);          // 32 KB (f then g)
    float*    g        = f + 2 * N;
    unsigned* bar      = (unsigned*)(ws + 384 * 1024);       // ~2.1 KB counters

    prep_kernel<<<dim3(16384 / 256), 256, 0, stream>>>(
        gen, gt, genPack, gtPack, wBaseGen, wBaseGt, f, out, bar);

    // 1024 blocks = exactly 4/CU on 256 CUs; __launch_bounds__(256,4) caps
    // VGPRs at 128 so all blocks are co-resident (persistent-kernel math).
    sinkhorn_main<<<dim3(N / RPB, 2), NT, 0, stream>>>(
        genPack, gtPack, wBaseGen, wBaseGt, f, g, bar, out);
}

// Round 3
// 873.680 us; speedup vs baseline: 1.7801x; 1.7801x over previous
//
#include <hip/hip_runtime.h>

// Entropic Sinkhorn EMD, B=2, N=4096, D=3, EPS=0.1, 20 iters.
// Round-9: fused persistent kernel WITHOUT cache flushes. Round-8 post-mortem:
// per-block agent ACQ_REL/acquire-fence barriers lowered to L2
// writeback+invalidate per block per phase (FETCH_SIZE 19.6MB = 41x full
// working set refetch; 32us/phase stall). Fix: pack{x,y,z,SHIFTL+nb} is
// CONSTANT (cached, L2 hot forever); only the 16KB/cloud duals (h2 = f_or_g *
// C10L) flow through the LLC via relaxed agent-scope atomics (sc1, no
// flushes). Sync = 16 per-chunk producer counters per (cloud,b): producer
// increments after vmcnt(0) confirms its dual stores reached the LLC;
// consumers do one batched 16-load poll per phase (wave 0 only). Monotonic,
// prep-zeroed (graph-replay safe), deadlock-free (1024 blocks co-resident at
// 4/CU, <=128 VGPR -- proven by round-8's completed spin barrier).

#define N     4096
#define NT    256
#define RPB   8      // rows per block -> grid (512, 2) = 1024 blocks = 4/CU
#define NGRP  16     // producer groups == column chunks (256 cols each)
#define CSTR  32     // counter stride in u32 (128 B, one line per counter)

constexpr float EPS_F  = 0.1f;
constexpr float SHIFT  = 60.0f;
constexpr float LOG_A  = -8.317766166719343f;   // -log(4096)
constexpr float C10L   = 14.426950408889634f;   // 10*log2(e)
constexpr float C20L   = 28.853900817779268f;   // 20*log2(e)
constexpr float SHIFTL = 86.56170245333781f;    // SHIFT*log2(e)
constexpr float NLN2T  = -0.06931471805599453f; // -ln2/10
constexpr float LN2    = 0.6931471805599453f;

extern "C" __device__ float __ocml_native_exp2_f32(float);

__device__ __forceinline__ float fast_exp2(float x) {
#if __has_builtin(__builtin_amdgcn_exp2f)
    return __builtin_amdgcn_exp2f(x);
#else
    return __ocml_native_exp2_f32(x);
#endif
}

__device__ __forceinline__ float rfl(float x) {
    return __int_as_float(__builtin_amdgcn_readfirstlane(__float_as_int(x)));
}

// LLC-resident (device-scope) accesses: performed at the coherence point,
// bypass L1/L2, require no cache maintenance for cross-XCD visibility.
__device__ __forceinline__ float llc_loadf(const float* p) {
    return __hip_atomic_load(p, __ATOMIC_RELAXED, __HIP_MEMORY_SCOPE_AGENT);
}
__device__ __forceinline__ void llc_storef(float* p, float v) {
    __hip_atomic_store(p, v, __ATOMIC_RELAXED, __HIP_MEMORY_SCOPE_AGENT);
}

// Pack {x,y,z, SHIFTL - 10L|p|^2} (CONSTANT for the whole solve); zero the
// dual arrays, chunk counters, and out. h2Gt = g*C10L = 0 is the required
// Sinkhorn initial state.
__global__ __launch_bounds__(256) void prep_kernel(
    const float* __restrict__ gen, const float* __restrict__ gt,
    float4* __restrict__ genPack, float4* __restrict__ gtPack,
    float* __restrict__ h2Gen, float* __restrict__ h2Gt,
    unsigned* __restrict__ cnt, float* __restrict__ out)
{
    int t = blockIdx.x * 256 + threadIdx.x;   // 0 .. 16383
    if (t < 2 * 2 * NGRP * CSTR) cnt[t] = 0u; // 2048 u32 of counters
    if (t < 8192) h2Gen[t] = 0.0f; else h2Gt[t - 8192] = 0.0f;
    int cloud = t >> 13;
    int idx   = t & 8191;                     // b*N + j
    const float* src = cloud ? gt : gen;
    float x = src[idx * 3 + 0];
    float y = src[idx * 3 + 1];
    float z = src[idx * 3 + 2];
    float nb = -C10L * fmaf(z, z, fmaf(y, y, x * x));   // -10L|p|^2
    (cloud ? gtPack : genPack)[idx] = make_float4(x, y, z, SHIFTL + nb);
    if (t == 0) out[0] = 0.0f;
}

// Batched distributed wait: wave 0 polls all 16 chunk counters (pipelined
// independent LLC loads), spins only if any is short of target.
__device__ __forceinline__ void wait_chunks(const unsigned* __restrict__ c0,
                                            unsigned target, int tid)
{
    if (tid < 64) {
        for (;;) {
            unsigned mn = 0xffffffffu;
            #pragma unroll
            for (int k = 0; k < NGRP; ++k) {
                unsigned c = __hip_atomic_load(c0 + k * CSTR, __ATOMIC_RELAXED,
                                               __HIP_MEMORY_SCOPE_AGENT);
                if (c < mn) mn = c;
            }
            if (mn >= target) break;
            __builtin_amdgcn_s_sleep(1);
        }
    }
    __syncthreads();
    asm volatile("" ::: "memory");   // keep h2 loads below the wait
}

// One half-sweep. Math identical to the verified round-6 sweep except
// w_j = pack.w + h2[j] (split constant/variable) instead of a fused pack.w.
__device__ __forceinline__ void sweep_phase(
    const float4* __restrict__ cp,   // column pack (constant, cached)
    const float*  __restrict__ h2c,  // column duals (LLC)
    float*        __restrict__ h2o,  // own-row dual out (+rowBase, LLC)
    const unsigned* __restrict__ cw, // counters to wait on
    unsigned*       __restrict__ ci, // own group counter to bump
    unsigned target,
    const float (&X)[RPB], const float (&Y)[RPB],
    const float (&Z)[RPB], const float (&S)[RPB],
    int tid, int grp, float (&sred)[RPB][4])
{
    wait_chunks(cw, target, tid);

    float acc[RPB];
    #pragma unroll
    for (int r = 0; r < RPB; ++r) acc[r] = 0.0f;

    #pragma unroll 2
    for (int g4 = 0; g4 < 4; ++g4) {
        const int base = ((g4 + grp) & 3) * 4;   // rotate chunk order per group
        float4 pr[4]; float hr[4];
        #pragma unroll
        for (int u = 0; u < 4; ++u) {
            int j = tid + NT * (base + u);
            pr[u] = cp[j];
            hr[u] = llc_loadf(h2c + j);
        }
        #pragma unroll
        for (int u = 0; u < 4; ++u) {
            float w = pr[u].w + hr[u];
            #pragma unroll
            for (int r = 0; r < RPB; ++r) {
                float t = fmaf(Z[r], pr[u].z, w);
                t = fmaf(Y[r], pr[u].y, t);
                t = fmaf(X[r], pr[u].x, t);
                acc[r] += fast_exp2(t + S[r]);
            }
        }
    }

    #pragma unroll
    for (int r = 0; r < RPB; ++r) {
        float a = acc[r];
        a += __shfl_xor(a, 32);
        a += __shfl_xor(a, 16);
        a += __shfl_xor(a, 8);
        a += __shfl_xor(a, 4);
        a += __shfl_xor(a, 2);
        a += __shfl_xor(a, 1);
        acc[r] = a;
    }
    const int wave = tid >> 6, lane = tid & 63;
    if (lane == 0) {
        #pragma unroll
        for (int r = 0; r < RPB; ++r) sred[r][wave] = acc[r];
    }
    __syncthreads();
    if (tid < RPB) {
        float s = (sred[tid][0] + sred[tid][1]) + (sred[tid][2] + sred[tid][3]);
        float dual = EPS_F * (LOG_A + SHIFT - log2f(s) * LN2);
        llc_storef(h2o + tid, dual * C10L);
        // physically order: dual stores reach the LLC before the arrival inc
        asm volatile("s_waitcnt vmcnt(0)" ::: "memory");
    }
    __syncthreads();
    if (tid == 0)
        __hip_atomic_fetch_add(ci, 1u, __ATOMIC_RELAXED,
                               __HIP_MEMORY_SCOPE_AGENT);
}

__global__ __launch_bounds__(NT, 4) void sinkhorn_main(
    const float4* __restrict__ packGen, const float4* __restrict__ packGt,
    float* __restrict__ h2Gen, float* __restrict__ h2Gt,
    unsigned* __restrict__ cnt, float* __restrict__ out)
{
    const int b       = blockIdx.y;
    const int tid     = threadIdx.x;
    const int rowBase = blockIdx.x * RPB;
    const int grp     = blockIdx.x >> 5;     // 0..15, 32 blocks each
    __shared__ float sred[RPB][4];

    const float4* rpG = packGen + (size_t)b * N + rowBase;
    const float4* rpT = packGt  + (size_t)b * N + rowBase;

    float XG[RPB], YG[RPB], ZG[RPB], SG[RPB];
    float XT[RPB], YT[RPB], ZT[RPB], ST[RPB];
    #pragma unroll
    for (int r = 0; r < RPB; ++r) {
        float4 q = rpG[r];
        XG[r] = rfl(q.x * C20L);
        YG[r] = rfl(q.y * C20L);
        ZG[r] = rfl(q.z * C20L);
        SG[r] = rfl(q.w - SHIFTL);           // -10L|p_i|^2
    }
    #pragma unroll
    for (int r = 0; r < RPB; ++r) {
        float4 q = rpT[r];
        XT[r] = rfl(q.x * C20L);
        YT[r] = rfl(q.y * C20L);
        ZT[r] = rfl(q.z * C20L);
        ST[r] = rfl(q.w - SHIFTL);
    }

    const float4* cpG = packGen + (size_t)b * N;
    const float4* cpT = packGt  + (size_t)b * N;
    float* hGen = h2Gen + (size_t)b * N;
    float* hGt  = h2Gt  + (size_t)b * N;
    unsigned* cntF = cnt + (size_t)(0 * 2 + b) * NGRP * CSTR;
    unsigned* cntG = cnt + (size_t)(1 * 2 + b) * NGRP * CSTR;

    for (unsigned t = 0; t < 20; ++t) {
        // f-update: rows = gen, cols = gt; needs h2Gt of g-update #(t-1)
        sweep_phase(cpT, hGt, hGen + rowBase, cntG, cntF + grp * CSTR,
                    32u * t, XG, YG, ZG, SG, tid, grp, sred);
        // g-update: rows = gt, cols = gen; needs h2Gen of f-update #t
        sweep_phase(cpG, hGen, hGt + rowBase, cntF, cntG + grp * CSTR,
                    32u * (t + 1), XT, YT, ZT, ST, tid, grp, sred);
    }

    // ---- loss: += 0.5 * sum_ij exp((f_i + g_j - C_ij)/EPS) * C_ij
    wait_chunks(cntG, 32u * 20, tid);
    {
        float Ax[RPB], Ay[RPB], Az[RPB], Ri[RPB], F2[RPB];
        #pragma unroll
        for (int r = 0; r < RPB; ++r) {
            float4 q = rpG[r];
            Ax[r] = rfl(q.x * -2.0f);
            Ay[r] = rfl(q.y * -2.0f);
            Az[r] = rfl(q.z * -2.0f);
            Ri[r] = rfl((q.w - SHIFTL) * NLN2T);        // |p_i|^2
            F2[r] = rfl(llc_loadf(hGen + rowBase + r)); // f_i * C10L
        }

        float acc = 0.0f;
        #pragma unroll 2
        for (int g4 = 0; g4 < 4; ++g4) {
            const int base = ((g4 + grp) & 3) * 4;
            float4 pr[4]; float hr[4];
            #pragma unroll
            for (int u = 0; u < 4; ++u) {
                int j = tid + NT * (base + u);
                pr[u] = cpT[j];
                hr[u] = llc_loadf(hGt + j);
            }
            #pragma unroll
            for (int u = 0; u < 4; ++u) {
                float G2 = hr[u];                        // g_j * C10L
                float rj = (pr[u].w - SHIFTL) * NLN2T;   // |p_j|^2
                #pragma unroll
                for (int r = 0; r < RPB; ++r) {
                    float cc = rj + Ri[r];
                    cc = fmaf(Az[r], pr[u].z, cc);
                    cc = fmaf(Ay[r], pr[u].y, cc);
                    cc = fmaf(Ax[r], pr[u].x, cc);
                    float arg = fmaf(cc, -C10L, G2 + F2[r]);
                    acc = fmaf(fast_exp2(arg), cc, acc);
                }
            }
        }

        acc += __shfl_xor(acc, 32);
        acc += __shfl_xor(acc, 16);
        acc += __shfl_xor(acc, 8);
        acc += __shfl_xor(acc, 4);
        acc += __shfl_xor(acc, 2);
        acc += __shfl_xor(acc, 1);
        const int wave = tid >> 6, lane = tid & 63;
        if (lane == 0) sred[0][wave] = acc;
        __syncthreads();
        if (tid == 0) {
            float t2 = (sred[0][0] + sred[0][1]) + (sred[0][2] + sred[0][3]);
            atomicAdd(out, t2 * 0.5f);
        }
    }
}

extern "C" void kernel_launch(void* const* d_in, const int* in_sizes, int n_in,
                              void* d_out, int out_size, void* d_ws, size_t ws_size,
                              hipStream_t stream) {
    const float* gen = (const float*)d_in[0];
    const float* gt  = (const float*)d_in[1];
    float* out = (float*)d_out;

    char* ws = (char*)d_ws;
    float4*   genPack = (float4*)ws;                       // 128 KB
    float4*   gtPack  = (float4*)(ws + 128 * 1024);        // 128 KB
    float*    h2Gen   = (float*)(ws + 256 * 1024);         // 32 KB
    float*    h2Gt    = (float*)(ws + 288 * 1024);         // 32 KB
    unsigned* cnt     = (unsigned*)(ws + 320 * 1024);      // 8 KB

    prep_kernel<<<dim3(16384 / 256), 256, 0, stream>>>(
        gen, gt, genPack, gtPack, h2Gen, h2Gt, cnt, out);

    sinkhorn_main<<<dim3(N / RPB, 2), NT, 0, stream>>>(
        genPack, gtPack, h2Gen, h2Gt, cnt, out);
}

// Round 4
// 685.159 us; speedup vs baseline: 2.2699x; 1.2751x over previous
//
#include <hip/hip_runtime.h>

// Entropic Sinkhorn EMD, B=2, N=4096, D=3, EPS=0.1, 20 iters.
// Round-10: round-9 skeleton (fused persistent kernel, no cache flushes,
// producer-group counters) with two targeted fixes from the 21us/phase
// post-mortem:
//  (a) RING-BUFFERED duals: phase t writes its 32KB dual vector to a fresh
//      address (fRing[t]/gRing[t+1]) via agent-scope stores (-> LLC); readers
//      use PLAIN CACHED loads. First touch per XCD misses to the LLC (fresh
//      by construction: address never read before its write within a launch;
//      across launches the prep/main dispatch boundaries invalidate L2 --
//      empirically proven by the round-6 multi-kernel dataflow). Cuts
//      16.8 MB/phase of same-line LLC reads to ~128 KB/phase.
//  (b) Poll de-contention: 32 spread counters (16 blocks/group), only lanes
//      <32 issue the poll load (one exec-masked instruction), __all ballot,
//      s_sleep(4) backoff.

#define N     4096
#define NT    256
#define RPB   8      // rows per block -> grid (512, 2) = 1024 blocks = 4/CU
#define NGRP  32     // producer groups per (cloud,b); 512/32 = 16 blocks each
#define GRPSZ 16
#define CSTR  32     // counter stride in u32 (128 B, one line per counter)

constexpr float EPS_F  = 0.1f;
constexpr float SHIFT  = 60.0f;
constexpr float LOG_A  = -8.317766166719343f;   // -log(4096)
constexpr float C10L   = 14.426950408889634f;   // 10*log2(e)
constexpr float C20L   = 28.853900817779268f;   // 20*log2(e)
constexpr float SHIFTL = 86.56170245333781f;    // SHIFT*log2(e)
constexpr float NLN2T  = -0.06931471805599453f; // -ln2/10
constexpr float LN2    = 0.6931471805599453f;

extern "C" __device__ float __ocml_native_exp2_f32(float);

__device__ __forceinline__ float fast_exp2(float x) {
#if __has_builtin(__builtin_amdgcn_exp2f)
    return __builtin_amdgcn_exp2f(x);
#else
    return __ocml_native_exp2_f32(x);
#endif
}

__device__ __forceinline__ float rfl(float x) {
    return __int_as_float(__builtin_amdgcn_readfirstlane(__float_as_int(x)));
}

// Agent-scope (LLC-performed) store: write-through to the coherence point so
// cross-XCD consumers' L2 misses fetch fresh data. No cache maintenance.
__device__ __forceinline__ void llc_storef(float* p, float v) {
    __hip_atomic_store(p, v, __ATOMIC_RELAXED, __HIP_MEMORY_SCOPE_AGENT);
}

// Pack {x,y,z, SHIFTL - 10L|p|^2} (CONSTANT for the whole solve); zero the
// counters, gRing version 0 (the Sinkhorn g=0 initial state), and out.
// Other ring versions are intentionally NOT touched (first-touch-after-write
// is what makes cached consumer reads coherent).
__global__ __launch_bounds__(256) void prep_kernel(
    const float* __restrict__ gen, const float* __restrict__ gt,
    float4* __restrict__ genPack, float4* __restrict__ gtPack,
    float* __restrict__ gRing0, unsigned* __restrict__ cnt,
    float* __restrict__ out)
{
    int t = blockIdx.x * 256 + threadIdx.x;   // 0 .. 16383
    if (t < 2 * 2 * NGRP * CSTR) cnt[t] = 0u; // 8192 u32 of counters
    if (t < 8192) gRing0[t] = 0.0f;           // g*C10L = 0 initial state
    int cloud = t >> 13;
    int idx   = t & 8191;                     // b*N + j
    const float* src = cloud ? gt : gen;
    float x = src[idx * 3 + 0];
    float y = src[idx * 3 + 1];
    float z = src[idx * 3 + 2];
    float nb = -C10L * fmaf(z, z, fmaf(y, y, x * x));   // -10L|p|^2
    (cloud ? gtPack : genPack)[idx] = make_float4(x, y, z, SHIFTL + nb);
    if (t == 0) out[0] = 0.0f;
}

// Distributed wait: lanes 0..31 of wave 0 each poll one counter (single
// exec-masked load per round), wave-wide ballot, sleep backoff.
__device__ __forceinline__ void wait_chunks(const unsigned* __restrict__ c0,
                                            unsigned target, int tid)
{
    if (tid < 64) {
        unsigned c = 0xffffffffu;
        const unsigned* pc = c0 + tid * CSTR;
        for (;;) {
            if (tid < NGRP)
                c = __hip_atomic_load(pc, __ATOMIC_RELAXED,
                                      __HIP_MEMORY_SCOPE_AGENT);
            if (__all(c >= target)) break;
            __builtin_amdgcn_s_sleep(4);
        }
    }
    __syncthreads();
    asm volatile("" ::: "memory");   // keep ring loads below the wait
}

// One half-sweep. Math identical to round-9; column duals are now CACHED
// loads from a fresh ring version (h2c), output duals go to ring h2o.
__device__ __forceinline__ void sweep_phase(
    const float4* __restrict__ cp,   // column pack (constant, cached)
    const float*  __restrict__ h2c,  // column duals, ring version (cached)
    float*        __restrict__ h2o,  // own-row dual out (+rowBase, LLC store)
    const unsigned* __restrict__ cw, // counters to wait on
    unsigned*       __restrict__ ci, // own group counter to bump
    unsigned target,
    const float (&X)[RPB], const float (&Y)[RPB],
    const float (&Z)[RPB], const float (&S)[RPB],
    int tid, int rot, float (&sred)[RPB][4])
{
    wait_chunks(cw, target, tid);

    float acc[RPB];
    #pragma unroll
    for (int r = 0; r < RPB; ++r) acc[r] = 0.0f;

    #pragma unroll 2
    for (int g4 = 0; g4 < 4; ++g4) {
        const int base = ((g4 + rot) & 3) * 4;   // spread first-touch lines
        float4 pr[4]; float hr[4];
        #pragma unroll
        for (int u = 0; u < 4; ++u) {
            int j = tid + NT * (base + u);
            pr[u] = cp[j];
            hr[u] = h2c[j];                      // cached (L2 after 1st touch)
        }
        #pragma unroll
        for (int u = 0; u < 4; ++u) {
            float w = pr[u].w + hr[u];
            #pragma unroll
            for (int r = 0; r < RPB; ++r) {
                float t = fmaf(Z[r], pr[u].z, w);
                t = fmaf(Y[r], pr[u].y, t);
                t = fmaf(X[r], pr[u].x, t);
                acc[r] += fast_exp2(t + S[r]);
            }
        }
    }

    #pragma unroll
    for (int r = 0; r < RPB; ++r) {
        float a = acc[r];
        a += __shfl_xor(a, 32);
        a += __shfl_xor(a, 16);
        a += __shfl_xor(a, 8);
        a += __shfl_xor(a, 4);
        a += __shfl_xor(a, 2);
        a += __shfl_xor(a, 1);
        acc[r] = a;
    }
    const int wave = tid >> 6, lane = tid & 63;
    if (lane == 0) {
        #pragma unroll
        for (int r = 0; r < RPB; ++r) sred[r][wave] = acc[r];
    }
    __syncthreads();
    if (tid < RPB) {
        float s = (sred[tid][0] + sred[tid][1]) + (sred[tid][2] + sred[tid][3]);
        float dual = EPS_F * (LOG_A + SHIFT - log2f(s) * LN2);
        llc_storef(h2o + tid, dual * C10L);
        // order: dual stores performed at LLC before the arrival inc
        asm volatile("s_waitcnt vmcnt(0)" ::: "memory");
    }
    __syncthreads();
    if (tid == 0)
        __hip_atomic_fetch_add(ci, 1u, __ATOMIC_RELAXED,
                               __HIP_MEMORY_SCOPE_AGENT);
}

__global__ __launch_bounds__(NT, 4) void sinkhorn_main(
    const float4* __restrict__ packGen, const float4* __restrict__ packGt,
    float* __restrict__ fRing,   // 20 versions x [2][N]
    float* __restrict__ gRing,   // 21 versions x [2][N]
    unsigned* __restrict__ cnt, float* __restrict__ out)
{
    const int b       = blockIdx.y;
    const int tid     = threadIdx.x;
    const int rowBase = blockIdx.x * RPB;
    const int grp     = blockIdx.x >> 4;     // 0..31, 16 blocks each
    const int rot     = blockIdx.x >> 5;     // chunk-order rotation
    __shared__ float sred[RPB][4];

    const float4* rpG = packGen + (size_t)b * N + rowBase;
    const float4* rpT = packGt  + (size_t)b * N + rowBase;

    float XG[RPB], YG[RPB], ZG[RPB], SG[RPB];
    float XT[RPB], YT[RPB], ZT[RPB], ST[RPB];
    #pragma unroll
    for (int r = 0; r < RPB; ++r) {
        float4 q = rpG[r];
        XG[r] = rfl(q.x * C20L);
        YG[r] = rfl(q.y * C20L);
        ZG[r] = rfl(q.z * C20L);
        SG[r] = rfl(q.w - SHIFTL);           // -10L|p_i|^2
    }
    #pragma unroll
    for (int r = 0; r < RPB; ++r) {
        float4 q = rpT[r];
        XT[r] = rfl(q.x * C20L);
        YT[r] = rfl(q.y * C20L);
        ZT[r] = rfl(q.z * C20L);
        ST[r] = rfl(q.w - SHIFTL);
    }

    const float4* cpG = packGen + (size_t)b * N;
    const float4* cpT = packGt  + (size_t)b * N;
    unsigned* cntF = cnt + (size_t)(0 * 2 + b) * NGRP * CSTR;
    unsigned* cntG = cnt + (size_t)(1 * 2 + b) * NGRP * CSTR;

    for (unsigned t = 0; t < 20; ++t) {
        // f-update: rows=gen, cols=gt; reads gRing[t], writes fRing[t]
        sweep_phase(cpT,
                    gRing + (size_t)t * 2 * N + (size_t)b * N,
                    fRing + (size_t)t * 2 * N + (size_t)b * N + rowBase,
                    cntG, cntF + grp * CSTR, GRPSZ * t,
                    XG, YG, ZG, SG, tid, rot, sred);
        // g-update: rows=gt, cols=gen; reads fRing[t], writes gRing[t+1]
        sweep_phase(cpG,
                    fRing + (size_t)t * 2 * N + (size_t)b * N,
                    gRing + (size_t)(t + 1) * 2 * N + (size_t)b * N + rowBase,
                    cntF, cntG + grp * CSTR, GRPSZ * (t + 1),
                    XT, YT, ZT, ST, tid, rot, sred);
    }

    // ---- loss: += 0.5 * sum_ij exp((f_i + g_j - C_ij)/EPS) * C_ij
    wait_chunks(cntG, GRPSZ * 20, tid);
    {
        const float* fFin = fRing + (size_t)19 * 2 * N + (size_t)b * N;
        const float* gFin = gRing + (size_t)20 * 2 * N + (size_t)b * N;

        float Ax[RPB], Ay[RPB], Az[RPB], Ri[RPB], F2[RPB];
        #pragma unroll
        for (int r = 0; r < RPB; ++r) {
            float4 q = rpG[r];
            Ax[r] = rfl(q.x * -2.0f);
            Ay[r] = rfl(q.y * -2.0f);
            Az[r] = rfl(q.z * -2.0f);
            Ri[r] = rfl((q.w - SHIFTL) * NLN2T);      // |p_i|^2
            F2[r] = rfl(fFin[rowBase + r]);           // f_i * C10L (cached)
        }

        float acc = 0.0f;
        #pragma unroll 2
        for (int g4 = 0; g4 < 4; ++g4) {
            const int base = ((g4 + rot) & 3) * 4;
            float4 pr[4]; float hr[4];
            #pragma unroll
            for (int u = 0; u < 4; ++u) {
                int j = tid + NT * (base + u);
                pr[u] = cpT[j];
                hr[u] = gFin[j];
            }
            #pragma unroll
            for (int u = 0; u < 4; ++u) {
                float G2 = hr[u];                        // g_j * C10L
                float rj = (pr[u].w - SHIFTL) * NLN2T;   // |p_j|^2
                #pragma unroll
                for (int r = 0; r < RPB; ++r) {
                    float cc = rj + Ri[r];
                    cc = fmaf(Az[r], pr[u].z, cc);
                    cc = fmaf(Ay[r], pr[u].y, cc);
                    cc = fmaf(Ax[r], pr[u].x, cc);
                    float arg = fmaf(cc, -C10L, G2 + F2[r]);
                    acc = fmaf(fast_exp2(arg), cc, acc);
                }
            }
        }

        acc += __shfl_xor(acc, 32);
        acc += __shfl_xor(acc, 16);
        acc += __shfl_xor(acc, 8);
        acc += __shfl_xor(acc, 4);
        acc += __shfl_xor(acc, 2);
        acc += __shfl_xor(acc, 1);
        const int wave = tid >> 6, lane = tid & 63;
        if (lane == 0) sred[0][wave] = acc;
        __syncthreads();
        if (tid == 0) {
            float t2 = (sred[0][0] + sred[0][1]) + (sred[0][2] + sred[0][3]);
            atomicAdd(out, t2 * 0.5f);
        }
    }
}

extern "C" void kernel_launch(void* const* d_in, const int* in_sizes, int n_in,
                              void* d_out, int out_size, void* d_ws, size_t ws_size,
                              hipStream_t stream) {
    const float* gen = (const float*)d_in[0];
    const float* gt  = (const float*)d_in[1];
    float* out = (float*)d_out;

    char* ws = (char*)d_ws;
    float4*   genPack = (float4*)ws;                       // 128 KB
    float4*   gtPack  = (float4*)(ws + 128 * 1024);        // 128 KB
    unsigned* cnt     = (unsigned*)(ws + 256 * 1024);      // 32 KB
    float*    fRing   = (float*)(ws + 288 * 1024);         // 20 x 32 KB
    float*    gRing   = (float*)(ws + 928 * 1024);         // 21 x 32 KB (ends ~1.6 MB)

    prep_kernel<<<dim3(16384 / 256), 256, 0, stream>>>(
        gen, gt, genPack, gtPack, gRing, cnt, out);

    sinkhorn_main<<<dim3(N / RPB, 2), NT, 0, stream>>>(
        genPack, gtPack, fRing, gRing, cnt, out);
}